// Round 12
// baseline (113.582 us; speedup 1.0000x reference)
//
#include <hip/hip_runtime.h>
#include <math.h>

typedef __attribute__((ext_vector_type(8))) short short8;
typedef __attribute__((ext_vector_type(16))) float f32x16;

namespace {
constexpr int kID = 512;    // input dim (K)
constexpr int kNO = 288;    // 128 in + 128 out + 32 eig (N)
constexpr int kBM = 32;     // tokens per block (M tile) -> grid = 512
constexpr int kNT = 9;      // N tiles of 32
constexpr int kKS = 32;     // k-steps of 16
constexpr int kCS = 296;    // LDS C stride (floats)
constexpr float kFactor = 0.1f;
constexpr int kCBytes = kBM * kCS * 4;     // C tile: 37888 B (A region 32 KiB aliases)
constexpr int kSmem   = kCBytes + kNO * 4; // + bias array = 39040 B
}

// RNE float -> bf16 (bit pattern).
__device__ __forceinline__ unsigned short f2bf(float f) {
    unsigned u = __float_as_uint(f);
    unsigned r = 0x7fffu + ((u >> 16) & 1u);
    return (unsigned short)((u + r) >> 16);
}

// ---------- Prep: W -> bf16 in 32x32x16 MFMA B-fragment order (r10-verified) ----------
// Fragment (kstep, nt, lane) holds W[n = nt*32 + (lane&31)][k = kstep*16 + (lane>>5)*8 + j].
__global__ void prep_w(const float* __restrict__ inW, const float* __restrict__ outW,
                       const float* __restrict__ eigW, unsigned short* __restrict__ wws) {
    int gid = blockIdx.x * 256 + threadIdx.x;      // [0, 32*9*64)
    if (gid >= kKS * kNT * 64) return;
    int lane  = gid & 63;
    int nt    = (gid >> 6) % kNT;
    int kstep = gid / (64 * kNT);
    int n = nt * 32 + (lane & 31);
    int k = kstep * 16 + (lane >> 5) * 8;
    const float* src = (n < 128 ? inW + (size_t)n * kID
                       : n < 256 ? outW + (size_t)(n - 128) * kID
                                 : eigW + (size_t)(n - 256) * kID) + k;
    unsigned short* dst = wws + (size_t)gid * 8;
    #pragma unroll
    for (int j = 0; j < 8; ++j) dst[j] = f2bf(src[j]);
}

// ---------- Main: 6-wave blocks, 32 tokens, 9 N-tiles {2,2,2,1,1,1} ----------
// 512 blocks; (384,5) -> VGPR<=102, 3 blocks/CU (18 waves/CU), LDS 117 KB/CU.
__global__ __launch_bounds__(384, 5)
void lrt_main(const float* __restrict__ x, const unsigned short* __restrict__ wws,
              const float* __restrict__ inB, const float* __restrict__ outB,
              const float* __restrict__ eigB, float* __restrict__ out) {
    __shared__ __align__(16) char smem[kSmem];
    char*  Ash = smem;                     // bf16 A fragments (32 KiB, phases 0/1)
    float* Cld = (float*)smem;             // fp32 C tile (phase 2+), aliases Ash
    float* sB  = (float*)(smem + kCBytes); // biases [288]

    const int tid  = threadIdx.x;
    const int tok0 = blockIdx.x * kBM;

    if (tid < kNO)
        sB[tid] = tid < 128 ? inB[tid] : tid < 256 ? outB[tid - 128] : eigB[tid - 256];

    // ---- Phase 0: stage x tile (32x512 fp32) as bf16 A-fragments in LDS ----
    // (identical to round-10-verified layout) slot = (t + 32*h), byte = ks*1024 +
    // slot*16, XOR-swizzled by (ks&7)<<4 on both write and read sides.
    for (int j = tid; j < kBM * 64; j += 384) {
        const int t  = j >> 6;
        const int k8 = j & 63;
        const float* src = x + (size_t)(tok0 + t) * kID + k8 * 8;
        float4 v0 = *(const float4*)(src);
        float4 v1 = *(const float4*)(src + 4);
        short8 a;
        a[0] = (short)f2bf(v0.x); a[1] = (short)f2bf(v0.y);
        a[2] = (short)f2bf(v0.z); a[3] = (short)f2bf(v0.w);
        a[4] = (short)f2bf(v1.x); a[5] = (short)f2bf(v1.y);
        a[6] = (short)f2bf(v1.z); a[7] = (short)f2bf(v1.w);
        const int ks = k8 >> 1, h = k8 & 1;
        int byte = ks * 1024 + (t + 32 * h) * 16;
        byte ^= (ks & 7) << 4;
        *(short8*)(Ash + byte) = a;
    }
    __syncthreads();

    // ---- Phase 1: K-loop. 1 ds_read_b128 + 1-2 uint4 B + 1-2 MFMA per step ----
    const int w    = tid >> 6;    // wave 0..5
    const int lane = tid & 63;
    const int ntb  = (w < 3) ? 2 * w : 3 + w;   // {0,2,4,6,7,8}
    const bool two = (w < 3);

    f32x16 acc0, acc1;
    #pragma unroll
    for (int i = 0; i < 16; ++i) { acc0[i] = 0.f; acc1[i] = 0.f; }

    const uint4* wp = (const uint4*)wws;
    #pragma unroll 4
    for (int ks = 0; ks < kKS; ++ks) {
        int byte = (ks * 1024 + lane * 16) ^ ((ks & 7) << 4);
        short8 a = *(const short8*)(Ash + byte);
        const size_t base = (size_t)(ks * kNT + ntb) * 64 + lane;
        uint4 b0 = wp[base];
        acc0 = __builtin_amdgcn_mfma_f32_32x32x16_bf16(
            a, __builtin_bit_cast(short8, b0), acc0, 0, 0, 0);
        if (two) {
            uint4 b1 = wp[base + 64];
            acc1 = __builtin_amdgcn_mfma_f32_32x32x16_bf16(
                a, __builtin_bit_cast(short8, b1), acc1, 0, 0, 0);
        }
    }
    __syncthreads();   // all A reads done; Cld may overwrite Ash

    // ---- Phase 2: spill C to LDS. D: row=(reg&3)+8*(reg>>2)+4*(lane>>5), col=lane&31 ----
    {
        const int c0 = lane & 31;
        const int h  = lane >> 5;
        #pragma unroll
        for (int rg = 0; rg < 16; ++rg) {
            const int trow = (rg & 3) + 8 * (rg >> 2) + 4 * h;
            Cld[trow * kCS + ntb * 32 + c0] = acc0[rg];
        }
        if (two) {
            #pragma unroll
            for (int rg = 0; rg < 16; ++rg) {
                const int trow = (rg & 3) + 8 * (rg >> 2) + 4 * h;
                Cld[trow * kCS + (ntb + 1) * 32 + c0] = acc1[rg];
            }
        }
    }
    __syncthreads();

    // ---- Phase 3: ortho_exp, 512 jobs (token, head, side) over 384 threads ----
    // E = sum_{p=0}^{15} skew^p / p!  (reference normalizer cancels analytically).
    for (int j3 = tid; j3 < 512; j3 += 384) {
        const int side = j3 & 1, head = (j3 >> 1) & 7, t = j3 >> 4;
        float* cr = Cld + t * kCS + side * 128 + head * 16;
        const float* bb = sB + side * 128 + head * 16;

        float M[16];
        #pragma unroll
        for (int c = 0; c < 4; ++c) {
            float4 v = *(const float4*)(cr + c * 4);
            M[c * 4 + 0] = v.x + bb[c * 4 + 0];
            M[c * 4 + 1] = v.y + bb[c * 4 + 1];
            M[c * 4 + 2] = v.z + bb[c * 4 + 2];
            M[c * 4 + 3] = v.w + bb[c * 4 + 3];
        }
        float S[16];
        #pragma unroll
        for (int a = 0; a < 4; ++a)
            #pragma unroll
            for (int b = 0; b < 4; ++b)
                S[a * 4 + b] = kFactor * (M[a * 4 + b] - M[b * 4 + a]);

        float R[16];
        #pragma unroll
        for (int i = 0; i < 16; ++i) R[i] = (i % 5 == 0) ? 1.0f : 0.0f;
        #pragma unroll
        for (int j = 15; j >= 1; --j) {
            const float inv = 1.0f / (float)j;
            float Rn[16];
            #pragma unroll
            for (int a = 0; a < 4; ++a)
                #pragma unroll
                for (int c = 0; c < 4; ++c) {
                    float s = S[a * 4 + 0] * R[0 * 4 + c];
                    s = fmaf(S[a * 4 + 1], R[1 * 4 + c], s);
                    s = fmaf(S[a * 4 + 2], R[2 * 4 + c], s);
                    s = fmaf(S[a * 4 + 3], R[3 * 4 + c], s);
                    Rn[a * 4 + c] = s * inv + ((a == c) ? 1.0f : 0.0f);
                }
            #pragma unroll
            for (int i = 0; i < 16; ++i) R[i] = Rn[i];
        }
        #pragma unroll
        for (int c = 0; c < 4; ++c)
            *(float4*)(cr + c * 4) = make_float4(R[c * 4 + 0], R[c * 4 + 1],
                                                 R[c * 4 + 2], R[c * 4 + 3]);
    }
    __syncthreads();

    // ---- Phase 4: transition = Eout * diag(tanh(eig)) * Ein, 256 jobs ----
    if (tid < 256) {
        const int t = tid >> 3, head = tid & 7;
        const float* cr = Cld + t * kCS;

        float Ein[16], Eout[16], d[4];
        #pragma unroll
        for (int i = 0; i < 16; ++i) Ein[i]  = cr[head * 16 + i];
        #pragma unroll
        for (int i = 0; i < 16; ++i) Eout[i] = cr[128 + head * 16 + i];
        #pragma unroll
        for (int b = 0; b < 4; ++b)
            d[b] = tanhf(cr[256 + head * 4 + b] + sB[256 + head * 4 + b]);

        float R[16];
        #pragma unroll
        for (int a = 0; a < 4; ++a) {
            float od0 = Eout[a * 4 + 0] * d[0];
            float od1 = Eout[a * 4 + 1] * d[1];
            float od2 = Eout[a * 4 + 2] * d[2];
            float od3 = Eout[a * 4 + 3] * d[3];
            #pragma unroll
            for (int c = 0; c < 4; ++c) {
                float s = od0 * Ein[0 * 4 + c];
                s = fmaf(od1, Ein[1 * 4 + c], s);
                s = fmaf(od2, Ein[2 * 4 + c], s);
                s = fmaf(od3, Ein[3 * 4 + c], s);
                R[a * 4 + c] = s;
            }
        }

        float* op = out + ((size_t)(tok0 + t) * 8 + head) * 16;
        #pragma unroll
        for (int a = 0; a < 4; ++a)
            *(float4*)(op + a * 4) = make_float4(R[a * 4 + 0], R[a * 4 + 1],
                                                 R[a * 4 + 2], R[a * 4 + 3]);
    }
}

extern "C" void kernel_launch(void* const* d_in, const int* in_sizes, int n_in,
                              void* d_out, int out_size, void* d_ws, size_t ws_size,
                              hipStream_t stream) {
    const float* x    = (const float*)d_in[0];
    const float* inB  = (const float*)d_in[1];
    const float* inW  = (const float*)d_in[2];
    const float* outB = (const float*)d_in[3];
    const float* outW = (const float*)d_in[4];
    const float* eigB = (const float*)d_in[5];
    const float* eigW = (const float*)d_in[6];
    float* out = (float*)d_out;

    unsigned short* wws = (unsigned short*)d_ws;   // 32*9*64*16 B = 288 KiB

    const int n_tokens = in_sizes[0] / kID;        // 16384
    const int n_blocks = n_tokens / kBM;           // 512

    prep_w<<<(kKS * kNT * 64 + 255) / 256, 256, 0, stream>>>(inW, outW, eigW, wws);
    lrt_main<<<n_blocks, 384, 0, stream>>>(x, wws, inB, outB, eigB, out);
}

// Round 13
// 102.307 us; speedup vs baseline: 1.1102x; 1.1102x over previous
//
#include <hip/hip_runtime.h>
#include <math.h>

typedef __attribute__((ext_vector_type(8))) short short8;
typedef __attribute__((ext_vector_type(16))) float f32x16;

namespace {
constexpr int kID = 512;    // input dim (K)
constexpr int kNO = 288;    // 128 in + 128 out + 32 eig (N)
constexpr int kBM = 32;     // tokens per block (M tile) -> grid = 512
constexpr int kNT = 9;      // N tiles of 32
constexpr int kKS = 32;     // k-steps of 16
constexpr int kCS = 296;    // LDS C stride (floats)
constexpr float kFactor = 0.1f;
constexpr int kCBytes = kBM * kCS * 4;     // C tile: 37888 B (A region 32 KiB aliases)
constexpr int kSmem   = kCBytes + kNO * 4; // + bias array = 39040 B
}

// RNE float -> bf16 (bit pattern).
__device__ __forceinline__ unsigned short f2bf(float f) {
    unsigned u = __float_as_uint(f);
    unsigned r = 0x7fffu + ((u >> 16) & 1u);
    return (unsigned short)((u + r) >> 16);
}

// ---------- Prep: W -> bf16 in 32x32x16 MFMA B-fragment order (verified r4/r10) ----------
// Fragment (kstep, nt, lane) holds W[n = nt*32 + (lane&31)][k = kstep*16 + (lane>>5)*8 + j].
__global__ void prep_w(const float* __restrict__ inW, const float* __restrict__ outW,
                       const float* __restrict__ eigW, unsigned short* __restrict__ wws) {
    int gid = blockIdx.x * 256 + threadIdx.x;      // [0, 32*9*64)
    if (gid >= kKS * kNT * 64) return;
    int lane  = gid & 63;
    int nt    = (gid >> 6) % kNT;
    int kstep = gid / (64 * kNT);
    int n = nt * 32 + (lane & 31);
    int k = kstep * 16 + (lane >> 5) * 8;
    const float* src = (n < 128 ? inW + (size_t)n * kID
                       : n < 256 ? outW + (size_t)(n - 128) * kID
                                 : eigW + (size_t)(n - 256) * kID) + k;
    unsigned short* dst = wws + (size_t)gid * 8;
    #pragma unroll
    for (int j = 0; j < 8; ++j) dst[j] = f2bf(src[j]);
}

// ---------- Main: 9 waves, 32 tokens, uniform 1 N-tile/wave (r10 structure) ----------
// (576,4): VGPR<=128 (no spill), LDS 39 KB -> up to 2 blocks/CU.
__global__ __launch_bounds__(576, 4)
void lrt_main(const float* __restrict__ x, const unsigned short* __restrict__ wws,
              const float* __restrict__ inB, const float* __restrict__ outB,
              const float* __restrict__ eigB, float* __restrict__ out) {
    __shared__ __align__(16) char smem[kSmem];
    char*  Ash = smem;                     // bf16 A fragments (32 KiB, phases 0/1)
    float* Cld = (float*)smem;             // fp32 C tile (phase 2+), aliases Ash
    float* sB  = (float*)(smem + kCBytes); // biases [288]

    const int tid  = threadIdx.x;
    const int tok0 = blockIdx.x * kBM;
    const int wv   = tid >> 6;    // wave = N tile index 0..8
    const int lane = tid & 63;

    if (tid < kNO)
        sB[tid] = tid < 128 ? inB[tid] : tid < 256 ? outB[tid - 128] : eigB[tid - 256];

    // ---- Pre-barrier B prefetch: first 4 fragments (independent of LDS) ----
    const uint4* wp = (const uint4*)wws;
    const uint4 b0 = wp[(size_t)(0 * kNT + wv) * 64 + lane];
    const uint4 b1 = wp[(size_t)(1 * kNT + wv) * 64 + lane];
    const uint4 b2 = wp[(size_t)(2 * kNT + wv) * 64 + lane];
    const uint4 b3 = wp[(size_t)(3 * kNT + wv) * 64 + lane];

    // ---- Phase 0: stage x (32x512 fp32) as bf16 A-fragments. Issue-early: ----
    // gather all chunks to regs, then cvt+write. (r10-verified layout+swizzle.)
    float4 xv0[4], xv1[4];
    #pragma unroll
    for (int c = 0; c < 4; ++c) {
        const int j = tid + c * 576;
        if (j < kBM * 64) {
            const float* src = x + (size_t)(tok0 + (j >> 6)) * kID + (j & 63) * 8;
            xv0[c] = *(const float4*)(src);
            xv1[c] = *(const float4*)(src + 4);
        }
    }
    #pragma unroll
    for (int c = 0; c < 4; ++c) {
        const int j = tid + c * 576;
        if (j < kBM * 64) {
            const int t = j >> 6, k8 = j & 63;
            short8 a;
            a[0] = (short)f2bf(xv0[c].x); a[1] = (short)f2bf(xv0[c].y);
            a[2] = (short)f2bf(xv0[c].z); a[3] = (short)f2bf(xv0[c].w);
            a[4] = (short)f2bf(xv1[c].x); a[5] = (short)f2bf(xv1[c].y);
            a[6] = (short)f2bf(xv1[c].z); a[7] = (short)f2bf(xv1[c].w);
            const int ks = k8 >> 1, h = k8 & 1;
            int byte = ks * 1024 + (t + 32 * h) * 16;
            byte ^= (ks & 7) << 4;
            *(short8*)(Ash + byte) = a;
        }
    }
    __syncthreads();

    // ---- Phase 1: K-loop. ks 0..3 consume prefetched B; rest unroll 8 ----
    f32x16 acc;
    #pragma unroll
    for (int i = 0; i < 16; ++i) acc[i] = 0.f;

    {
        #pragma unroll
        for (int ks = 0; ks < 4; ++ks) {
            int byte = (ks * 1024 + lane * 16) ^ ((ks & 7) << 4);
            short8 a = *(const short8*)(Ash + byte);
            const uint4 b = (ks == 0) ? b0 : (ks == 1) ? b1 : (ks == 2) ? b2 : b3;
            acc = __builtin_amdgcn_mfma_f32_32x32x16_bf16(
                a, __builtin_bit_cast(short8, b), acc, 0, 0, 0);
        }
        #pragma unroll 8
        for (int ks = 4; ks < kKS; ++ks) {
            int byte = (ks * 1024 + lane * 16) ^ ((ks & 7) << 4);
            short8 a = *(const short8*)(Ash + byte);
            uint4  b = wp[(size_t)(ks * kNT + wv) * 64 + lane];
            acc = __builtin_amdgcn_mfma_f32_32x32x16_bf16(
                a, __builtin_bit_cast(short8, b), acc, 0, 0, 0);
        }
    }
    __syncthreads();   // all A reads done; Cld may overwrite Ash

    // ---- Phase 2: spill C to LDS. D: row=(reg&3)+8*(reg>>2)+4*(lane>>5), col=lane&31 ----
    {
        const int col = wv * 32 + (lane & 31);
        const int h   = lane >> 5;
        #pragma unroll
        for (int rg = 0; rg < 16; ++rg) {
            const int trow = (rg & 3) + 8 * (rg >> 2) + 4 * h;
            Cld[trow * kCS + col] = acc[rg];
        }
    }
    __syncthreads();

    // ---- Phase 3: ortho_exp, 512 jobs (token, head, side) ----
    // E = sum_{p=0}^{15} skew^p / p!  (reference normalizer cancels analytically).
    if (tid < 512) {
        const int side = tid & 1, head = (tid >> 1) & 7, t = tid >> 4;
        float* cr = Cld + t * kCS + side * 128 + head * 16;
        const float* bb = sB + side * 128 + head * 16;

        float M[16];
        #pragma unroll
        for (int c = 0; c < 4; ++c) {
            float4 v = *(const float4*)(cr + c * 4);
            M[c * 4 + 0] = v.x + bb[c * 4 + 0];
            M[c * 4 + 1] = v.y + bb[c * 4 + 1];
            M[c * 4 + 2] = v.z + bb[c * 4 + 2];
            M[c * 4 + 3] = v.w + bb[c * 4 + 3];
        }
        float S[16];
        #pragma unroll
        for (int a = 0; a < 4; ++a)
            #pragma unroll
            for (int b = 0; b < 4; ++b)
                S[a * 4 + b] = kFactor * (M[a * 4 + b] - M[b * 4 + a]);

        float R[16];
        #pragma unroll
        for (int i = 0; i < 16; ++i) R[i] = (i % 5 == 0) ? 1.0f : 0.0f;
        #pragma unroll
        for (int j = 15; j >= 1; --j) {
            const float inv = 1.0f / (float)j;
            float Rn[16];
            #pragma unroll
            for (int a = 0; a < 4; ++a)
                #pragma unroll
                for (int c = 0; c < 4; ++c) {
                    float s = S[a * 4 + 0] * R[0 * 4 + c];
                    s = fmaf(S[a * 4 + 1], R[1 * 4 + c], s);
                    s = fmaf(S[a * 4 + 2], R[2 * 4 + c], s);
                    s = fmaf(S[a * 4 + 3], R[3 * 4 + c], s);
                    Rn[a * 4 + c] = s * inv + ((a == c) ? 1.0f : 0.0f);
                }
            #pragma unroll
            for (int i = 0; i < 16; ++i) R[i] = Rn[i];
        }
        #pragma unroll
        for (int c = 0; c < 4; ++c)
            *(float4*)(cr + c * 4) = make_float4(R[c * 4 + 0], R[c * 4 + 1],
                                                 R[c * 4 + 2], R[c * 4 + 3]);
    }
    __syncthreads();

    // ---- Phase 4: transition = Eout * diag(tanh(eig)) * Ein, 256 jobs ----
    if (tid < 256) {
        const int t = tid >> 3, head = tid & 7;
        const float* cr = Cld + t * kCS;

        float Ein[16], Eout[16], d[4];
        #pragma unroll
        for (int i = 0; i < 16; ++i) Ein[i]  = cr[head * 16 + i];
        #pragma unroll
        for (int i = 0; i < 16; ++i) Eout[i] = cr[128 + head * 16 + i];
        #pragma unroll
        for (int b = 0; b < 4; ++b)
            d[b] = tanhf(cr[256 + head * 4 + b] + sB[256 + head * 4 + b]);

        float R[16];
        #pragma unroll
        for (int a = 0; a < 4; ++a) {
            float od0 = Eout[a * 4 + 0] * d[0];
            float od1 = Eout[a * 4 + 1] * d[1];
            float od2 = Eout[a * 4 + 2] * d[2];
            float od3 = Eout[a * 4 + 3] * d[3];
            #pragma unroll
            for (int c = 0; c < 4; ++c) {
                float s = od0 * Ein[0 * 4 + c];
                s = fmaf(od1, Ein[1 * 4 + c], s);
                s = fmaf(od2, Ein[2 * 4 + c], s);
                s = fmaf(od3, Ein[3 * 4 + c], s);
                R[a * 4 + c] = s;
            }
        }

        float* op = out + ((size_t)(tok0 + t) * 8 + head) * 16;
        #pragma unroll
        for (int a = 0; a < 4; ++a)
            *(float4*)(op + a * 4) = make_float4(R[a * 4 + 0], R[a * 4 + 1],
                                                 R[a * 4 + 2], R[a * 4 + 3]);
    }
}

extern "C" void kernel_launch(void* const* d_in, const int* in_sizes, int n_in,
                              void* d_out, int out_size, void* d_ws, size_t ws_size,
                              hipStream_t stream) {
    const float* x    = (const float*)d_in[0];
    const float* inB  = (const float*)d_in[1];
    const float* inW  = (const float*)d_in[2];
    const float* outB = (const float*)d_in[3];
    const float* outW = (const float*)d_in[4];
    const float* eigB = (const float*)d_in[5];
    const float* eigW = (const float*)d_in[6];
    float* out = (float*)d_out;

    unsigned short* wws = (unsigned short*)d_ws;   // 32*9*64*16 B = 288 KiB

    const int n_tokens = in_sizes[0] / kID;        // 16384
    const int n_blocks = n_tokens / kBM;           // 512

    prep_w<<<(kKS * kNT * 64 + 255) / 256, 256, 0, stream>>>(inW, outW, eigW, wws);
    lrt_main<<<n_blocks, 576, 0, stream>>>(x, wws, inB, outB, eigB, out);
}